// Round 15
// baseline (2606.246 us; speedup 1.0000x reference)
//
#include <hip/hip_runtime.h>

// Problem dims (fixed by setup_inputs): T=256, B=64, I=512, H=2048
#define T_DIM 256
#define B_DIM 64
#define I_DIM 512
#define H_DIM 2048
#define BH (B_DIM * H_DIM)      // 131072 floats per timestep slice
#define NBLK 256                // persistent grid: 1 block per CU
#define PUB_U64 32768           // one parity: 16384 slots * 2 u64 (256 KB)

typedef __attribute__((ext_vector_type(8))) short bf16x8;
typedef __attribute__((ext_vector_type(4))) float f32x4;

// ---------------------------------------------------------------------
// Agent-scope ops (validated R4-R14): relaxed sc-bit global ops serviced
// at the device coherence point (MALL) — coherent, uncached, no fences.
// R12/R13 lesson: pub-style rewritten addresses MUST use these; normal
// loads only for touch-once private streams (xin/out regions).
// ---------------------------------------------------------------------
__device__ __forceinline__ unsigned aloadU32(const unsigned* p) {
  return __hip_atomic_load(p, __ATOMIC_RELAXED, __HIP_MEMORY_SCOPE_AGENT);
}
__device__ __forceinline__ unsigned long long aload64(
    const unsigned long long* p) {
  return __hip_atomic_load(p, __ATOMIC_RELAXED, __HIP_MEMORY_SCOPE_AGENT);
}
__device__ __forceinline__ void astore4(float* p, float a) {
  union { unsigned u; float f; } c; c.f = a;
  __hip_atomic_store((unsigned*)p, c.u, __ATOMIC_RELAXED,
                     __HIP_MEMORY_SCOPE_AGENT);
}
__device__ __forceinline__ void astoreU(unsigned long long* p,
                                        unsigned long long v) {
  __hip_atomic_store(p, v, __ATOMIC_RELAXED, __HIP_MEMORY_SCOPE_AGENT);
}

// bf16 split helpers
__device__ __forceinline__ unsigned bf16_rne(float x) {
  union { float f; unsigned u; } c; c.f = x;
  return (c.u + 0x7FFFu + ((c.u >> 16) & 1u)) >> 16;
}
__device__ __forceinline__ float bf16_to_f(unsigned b) {
  union { float f; unsigned u; } c; c.u = b << 16; return c.f;
}
__device__ __forceinline__ void cvt_pair(float x0, float x1,
                                         unsigned& hi, unsigned& lo) {
  unsigned h0 = bf16_rne(x0), h1 = bf16_rne(x1);
  float r0 = x0 - bf16_to_f(h0), r1 = x1 - bf16_to_f(h1);
  unsigned l0 = bf16_rne(r0), l1 = bf16_rne(r1);
  hi = h0 | (h1 << 16);
  lo = l0 | (l1 << 16);
}
__device__ __forceinline__ void cvt8(const float* s, uint4& hi, uint4& lo) {
  float4 a = *(const float4*)s;
  float4 b = *(const float4*)(s + 4);
  cvt_pair(a.x, a.y, hi.x, lo.x);
  cvt_pair(a.z, a.w, hi.y, lo.y);
  cvt_pair(b.x, b.y, hi.z, lo.z);
  cvt_pair(b.z, b.w, hi.w, lo.w);
}

// =====================================================================
// Kernel A (R14, unchanged): MFMA split-bf16 xin GEMM (~108us).
// xin = x @ W_ih^T + b_ih + b_hh ; rows m<64 fold t=0.
// =====================================================================
__global__ __launch_bounds__(256) void xin_gemm(
    const float* __restrict__ x, const float* __restrict__ Wih,
    const float* __restrict__ bih, const float* __restrict__ bhh,
    float* __restrict__ out)
{
  __shared__ __align__(16) uint4 Xhi[512], Xlo[512];
  __shared__ __align__(16) uint4 Ghi[512], Glo[512];

  const int tid = threadIdx.x;
  const int nb = blockIdx.x & 15, mb = blockIdx.x >> 4;
  const int m0 = mb * 128, n0 = nb * 128;
  const int lane = tid & 63, wid = tid >> 6;
  const int wm = wid & 1, wn = wid >> 1;
  const int fq = lane >> 4, fr = lane & 15;

  f32x4 acc[4][4];
  #pragma unroll
  for (int i = 0; i < 4; ++i)
    #pragma unroll
    for (int j = 0; j < 4; ++j) acc[i][j] = (f32x4){0.f, 0.f, 0.f, 0.f};

  for (int k0 = 0; k0 < I_DIM; k0 += 32) {
    __syncthreads();
    #pragma unroll
    for (int h = 0; h < 2; ++h) {
      const int f = tid + h * 256;
      const int r = f >> 2, o = f & 3;
      const int s = (r >> 4) * 64 + o * 16 + (r & 15);
      uint4 hi, lo;
      cvt8(&x[(size_t)(m0 + r) * I_DIM + k0 + o * 8], hi, lo);
      Xhi[s] = hi; Xlo[s] = lo;
      cvt8(&Wih[(size_t)(n0 + r) * I_DIM + k0 + o * 8], hi, lo);
      Ghi[s] = hi; Glo[s] = lo;
    }
    __syncthreads();

    uint4 ahi[4], alo[4];
    #pragma unroll
    for (int mt = 0; mt < 4; ++mt) {
      ahi[mt] = Xhi[(wm * 4 + mt) * 64 + lane];
      alo[mt] = Xlo[(wm * 4 + mt) * 64 + lane];
    }
    #pragma unroll
    for (int nt = 0; nt < 4; ++nt) {
      const uint4 bhv = Ghi[(wn * 4 + nt) * 64 + lane];
      const uint4 blv = Glo[(wn * 4 + nt) * 64 + lane];
      #pragma unroll
      for (int mt = 0; mt < 4; ++mt) {
        acc[mt][nt] = __builtin_amdgcn_mfma_f32_16x16x32_bf16(
            *(const bf16x8*)&ahi[mt], *(const bf16x8*)&bhv, acc[mt][nt],
            0, 0, 0);
        acc[mt][nt] = __builtin_amdgcn_mfma_f32_16x16x32_bf16(
            *(const bf16x8*)&ahi[mt], *(const bf16x8*)&blv, acc[mt][nt],
            0, 0, 0);
        acc[mt][nt] = __builtin_amdgcn_mfma_f32_16x16x32_bf16(
            *(const bf16x8*)&alo[mt], *(const bf16x8*)&bhv, acc[mt][nt],
            0, 0, 0);
      }
    }
  }

  float bb[4];
  #pragma unroll
  for (int nt = 0; nt < 4; ++nt) {
    const int n = n0 + wn * 64 + nt * 16 + fr;
    bb[nt] = bih[n] + bhh[n];
  }
  #pragma unroll
  for (int mt = 0; mt < 4; ++mt)
    #pragma unroll
    for (int j = 0; j < 4; ++j) {
      const int m = m0 + wm * 64 + mt * 16 + fq * 4 + j;
      const bool fold = (m < B_DIM);
      #pragma unroll
      for (int nt = 0; nt < 4; ++nt) {
        const int n = n0 + wn * 64 + nt * 16 + fr;
        float v = acc[mt][nt][j] + bb[nt];
        if (fold) v = 0.01f * fmaxf(v, 0.f);
        out[(size_t)m * H_DIM + n] = v;
      }
    }
}

// =====================================================================
// Kernel B (R15): R11 dataflow + three chain cuts:
//  (1) out stores AFTER flag (block-private, never gate consumers) ->
//      drain covers only the 2 publish stores.
//  (2) drain+flag on wave 0 only; one less __syncthreads per step.
//  (3) per-kc flag gating + 3-deep load pipeline: kc's loads issue as
//      soon as its own 2 producers (wid*32+kc*2, +1) have flagged —
//      early loads fly while late producers publish.
// Parity-overwrite invariant unchanged: publish of h[t] still requires
// all 16 kc waits of all 4 waves (= all 128 group flags >= t), which
// proves every reader of the parity being overwritten has moved on.
// =====================================================================
__global__ __launch_bounds__(256) void ctrnn_scan(
    const float* __restrict__ Whh, float* out,
    unsigned long long* __restrict__ pub, unsigned* slots)
{
  __shared__ __align__(16) uint4 Whi[4096];   // 64 KB
  __shared__ __align__(16) uint4 Wlo[4096];   // 64 KB
  __shared__ __align__(16) f32x4 Red[512];    // 8 KB
  __shared__ unsigned short Hs[32][16];       // 1 KB bf16 publish staging

  const int tid = threadIdx.x, bid = blockIdx.x;
  const int nb = bid & 127, bh = bid >> 7;
  const int n0 = nb * 16, b0 = bh * 32;

  const int lane = tid & 63, wid = tid >> 6;
  const int fq = lane >> 4, fr = lane & 15;

  // ---- stage W slice ONCE: rows n0..n0+16, all k, frag-packed hi/lo ----
  for (int s = tid; s < 4096; s += 256) {
    const int kcg = s >> 6, l = s & 63;
    const int n = n0 + (l & 15), k = kcg * 32 + (l >> 4) * 8;
    uint4 hi, lo;
    cvt8(&Whh[(size_t)n * H_DIM + k], hi, lo);
    Whi[s] = hi; Wlo[s] = lo;
  }

  // ---- ownership mapping (MFMA C layout: col=lane&15=n, row=b) ----
  const int bt = tid >> 7, jh = (tid >> 6) & 1, ln = tid & 63;
  const int rfr = ln & 15, rfq = ln >> 4;
  const int bl0 = bt * 16 + rfq * 4 + jh * 2;            // local b of 1st
  const size_t oa0 = (size_t)(b0 + bl0) * H_DIM + n0 + rfr;
  const size_t oa1 = oa0 + H_DIM;

  // fp32 h state in registers (h[0] = out[0], t=0 folded in xin_gemm)
  float h0 = out[oa0];
  float h1 = out[oa1];

  // ---- publish h[0] as bf16 frags to pub parity 0, then flag = 1 ----
  Hs[bl0][rfr]     = (unsigned short)bf16_rne(h0);
  Hs[bl0 + 1][rfr] = (unsigned short)bf16_rne(h1);
  __syncthreads();   // also covers W staging completion
  if (tid < 64) {
    const int b_l = tid & 31, h8 = tid >> 5;
    const uint4 frag = *(const uint4*)&Hs[b_l][h8 * 8];
    const size_t slot = (size_t)(nb * 2 + h8) * 64 + b0 + b_l;
    astoreU(&pub[slot * 2 + 0], ((const unsigned long long*)&frag)[0]);
    astoreU(&pub[slot * 2 + 1], ((const unsigned long long*)&frag)[1]);
    asm volatile("s_waitcnt vmcnt(0)" ::: "memory");
    if (tid == 0)
      __hip_atomic_store(slots + (size_t)bid * 16, 1u, __ATOMIC_RELAXED,
                         __HIP_MEMORY_SCOPE_AGENT);
  }

  // flag base for my wave's 32 producers: blocks (bh, wid*32 + 0..31)
  const unsigned* fb = slots + (size_t)(bh * 128 + wid * 32) * 16;

  const int baseA64 = (wid * 4096 + fq * 64 + b0 + fr) * 2;  // u64 units
  const int baseB = wid * 1024;                              // +kc*64+lane

  for (int t = 1; t < T_DIM; ++t) {
    // xin prefetch (block-private normal load; hides under kc-0 wait)
    const float xin0 = out[(size_t)t * BH + oa0];
    const float xin1 = out[(size_t)t * BH + oa1];
    asm volatile("" :: "v"(xin0), "v"(xin1));  // keep loads here

    const unsigned long long* pr = pub + (size_t)((t - 1) & 1) * PUB_U64;

    // ---- per-kc gated, 3-deep pipelined A-frag loads + MFMA ----
    auto waitkc = [&](int kc) {
      const unsigned* fa = fb + kc * 32;   // (kc*2)*16 u32s
      for (int it = 0; it < (1 << 17); ++it) {
        if (aloadU32(fa) >= (unsigned)t &&
            aloadU32(fa + 16) >= (unsigned)t) break;
        __builtin_amdgcn_s_sleep(1);
      }
    };
    auto loadkc = [&](int kc, unsigned long long* B) {
      const int off = baseA64 + kc * 512;
      B[0] = aload64(pr + off);      B[1] = aload64(pr + off + 1);
      B[2] = aload64(pr + off + 32); B[3] = aload64(pr + off + 33);
    };

    unsigned long long B[3][4];
    waitkc(0); loadkc(0, B[0]);
    waitkc(1); loadkc(1, B[1]);

    f32x4 acc0 = {0.f, 0.f, 0.f, 0.f}, acc1 = {0.f, 0.f, 0.f, 0.f};
    #pragma unroll
    for (int kc = 0; kc < 16; ++kc) {
      if (kc + 2 < 16) { waitkc(kc + 2); loadkc(kc + 2, B[(kc + 2) % 3]); }
      const uint4 bh4 = Whi[baseB + kc * 64 + lane];
      const uint4 bl4 = Wlo[baseB + kc * 64 + lane];
      union { unsigned long long u[2]; bf16x8 v; } a0c, a1c;
      a0c.u[0] = B[kc % 3][0]; a0c.u[1] = B[kc % 3][1];
      a1c.u[0] = B[kc % 3][2]; a1c.u[1] = B[kc % 3][3];
      acc0 = __builtin_amdgcn_mfma_f32_16x16x32_bf16(
          a0c.v, *(const bf16x8*)&bh4, acc0, 0, 0, 0);
      acc0 = __builtin_amdgcn_mfma_f32_16x16x32_bf16(
          a0c.v, *(const bf16x8*)&bl4, acc0, 0, 0, 0);
      acc1 = __builtin_amdgcn_mfma_f32_16x16x32_bf16(
          a1c.v, *(const bf16x8*)&bh4, acc1, 0, 0, 0);
      acc1 = __builtin_amdgcn_mfma_f32_16x16x32_bf16(
          a1c.v, *(const bf16x8*)&bl4, acc1, 0, 0, 0);
    }

    // ---- cross-wave K reduce ----
    Red[(wid * 2 + 0) * 64 + lane] = acc0;
    Red[(wid * 2 + 1) * 64 + lane] = acc1;
    __syncthreads();

    float s0 = 0.f, s1 = 0.f;
    #pragma unroll
    for (int w = 0; w < 4; ++w) {
      const float2 p = *(const float2*)(
          (const char*)&Red[(w * 2 + bt) * 64 + ln] + jh * 8);
      s0 += p.x; s1 += p.y;
    }

    // ---- leaky-relu update (fp32 register state) ----
    h0 = 0.99f * h0 + 0.01f * fmaxf(xin0 + s0, 0.f);
    h1 = 0.99f * h1 + 0.01f * fmaxf(xin1 + s1, 0.f);

    // ---- publish path FIRST (critical): Hs -> sync -> wave0 publish
    //      -> wave0 drain (publish stores only) -> flag ----
    Hs[bl0][rfr]     = (unsigned short)bf16_rne(h0);
    Hs[bl0 + 1][rfr] = (unsigned short)bf16_rne(h1);
    __syncthreads();
    if (t < T_DIM - 1 && tid < 64) {
      const int b_l = tid & 31, h8 = tid >> 5;
      const uint4 frag = *(const uint4*)&Hs[b_l][h8 * 8];
      const size_t slot = (size_t)(nb * 2 + h8) * 64 + b0 + b_l;
      unsigned long long* pw =
          pub + (size_t)(t & 1) * PUB_U64 + slot * 2;
      astoreU(pw + 0, ((const unsigned long long*)&frag)[0]);
      astoreU(pw + 1, ((const unsigned long long*)&frag)[1]);
      asm volatile("s_waitcnt vmcnt(0)" ::: "memory");
      if (tid == 0)
        __hip_atomic_store(slots + (size_t)bid * 16, (unsigned)(t + 1),
                           __ATOMIC_RELAXED, __HIP_MEMORY_SCOPE_AGENT);
    }

    // ---- out stores AFTER flag (block-private; off the critical path) ----
    astore4(&out[(size_t)t * BH + oa0], h0);
    astore4(&out[(size_t)t * BH + oa1], h1);
    if (t == T_DIM - 1) {
      astore4(&out[(size_t)T_DIM * BH + oa0], h0);  // h_last
      astore4(&out[(size_t)T_DIM * BH + oa1], h1);
    }
  }
}

// =====================================================================
extern "C" void kernel_launch(void* const* d_in, const int* in_sizes, int n_in,
                              void* d_out, int out_size, void* d_ws, size_t ws_size,
                              hipStream_t stream) {
  const float* x    = (const float*)d_in[0];
  const float* Wih  = (const float*)d_in[1];
  const float* bih  = (const float*)d_in[2];
  const float* Whh  = (const float*)d_in[3];
  const float* bhh  = (const float*)d_in[4];
  float* out = (float*)d_out;

  unsigned* slots = (unsigned*)d_ws;                          // 16 KB flags
  unsigned long long* pub =
      (unsigned long long*)((char*)d_ws + 32768);             // 512 KB

  hipMemsetAsync(d_ws, 0, 32768, stream);  // reset flags every call

  xin_gemm<<<dim3(2048), dim3(256), 0, stream>>>(x, Wih, bih, bhh, out);
  ctrnn_scan<<<dim3(NBLK), dim3(256), 0, stream>>>(Whh, out, pub, slots);
}

// Round 16
// 1478.073 us; speedup vs baseline: 1.7633x; 1.7633x over previous
//
#include <hip/hip_runtime.h>

// Problem dims (fixed by setup_inputs): T=256, B=64, I=512, H=2048
#define T_DIM 256
#define B_DIM 64
#define I_DIM 512
#define H_DIM 2048
#define BH (B_DIM * H_DIM)      // 131072 floats per timestep slice
#define NBLK 256                // persistent grid: 1 block per CU
#define PUB_U64 32768           // one parity: 16384 slots * 2 u64 (256 KB)

typedef __attribute__((ext_vector_type(8))) short bf16x8;
typedef __attribute__((ext_vector_type(4))) float f32x4;

// ---------------------------------------------------------------------
// Agent-scope ops (validated R4-R14): relaxed sc-bit global ops serviced
// at the device coherence point (MALL) — coherent, uncached, no fences.
// R12/R13 lesson: pub-style rewritten addresses MUST use these; normal
// loads only for touch-once private streams (xin/out regions).
// R15 lesson: flag polling must stay ONE wave-parallel coalesced check
// (wait on max producer latency), never per-kc serial round-trips (sum).
// ---------------------------------------------------------------------
__device__ __forceinline__ unsigned aloadU32(const unsigned* p) {
  return __hip_atomic_load(p, __ATOMIC_RELAXED, __HIP_MEMORY_SCOPE_AGENT);
}
__device__ __forceinline__ unsigned long long aload64(
    const unsigned long long* p) {
  return __hip_atomic_load(p, __ATOMIC_RELAXED, __HIP_MEMORY_SCOPE_AGENT);
}
__device__ __forceinline__ void astore4(float* p, float a) {
  union { unsigned u; float f; } c; c.f = a;
  __hip_atomic_store((unsigned*)p, c.u, __ATOMIC_RELAXED,
                     __HIP_MEMORY_SCOPE_AGENT);
}
__device__ __forceinline__ void astoreU(unsigned long long* p,
                                        unsigned long long v) {
  __hip_atomic_store(p, v, __ATOMIC_RELAXED, __HIP_MEMORY_SCOPE_AGENT);
}

// bf16 split helpers
__device__ __forceinline__ unsigned bf16_rne(float x) {
  union { float f; unsigned u; } c; c.f = x;
  return (c.u + 0x7FFFu + ((c.u >> 16) & 1u)) >> 16;
}
__device__ __forceinline__ float bf16_to_f(unsigned b) {
  union { float f; unsigned u; } c; c.u = b << 16; return c.f;
}
__device__ __forceinline__ void cvt_pair(float x0, float x1,
                                         unsigned& hi, unsigned& lo) {
  unsigned h0 = bf16_rne(x0), h1 = bf16_rne(x1);
  float r0 = x0 - bf16_to_f(h0), r1 = x1 - bf16_to_f(h1);
  unsigned l0 = bf16_rne(r0), l1 = bf16_rne(r1);
  hi = h0 | (h1 << 16);
  lo = l0 | (l1 << 16);
}
__device__ __forceinline__ void cvt8(const float* s, uint4& hi, uint4& lo) {
  float4 a = *(const float4*)s;
  float4 b = *(const float4*)(s + 4);
  cvt_pair(a.x, a.y, hi.x, lo.x);
  cvt_pair(a.z, a.w, hi.y, lo.y);
  cvt_pair(b.x, b.y, hi.z, lo.z);
  cvt_pair(b.z, b.w, hi.w, lo.w);
}

// =====================================================================
// Kernel A (R14, unchanged): MFMA split-bf16 xin GEMM (~108us).
// xin = x @ W_ih^T + b_ih + b_hh ; rows m<64 fold t=0.
// =====================================================================
__global__ __launch_bounds__(256) void xin_gemm(
    const float* __restrict__ x, const float* __restrict__ Wih,
    const float* __restrict__ bih, const float* __restrict__ bhh,
    float* __restrict__ out)
{
  __shared__ __align__(16) uint4 Xhi[512], Xlo[512];
  __shared__ __align__(16) uint4 Ghi[512], Glo[512];

  const int tid = threadIdx.x;
  const int nb = blockIdx.x & 15, mb = blockIdx.x >> 4;
  const int m0 = mb * 128, n0 = nb * 128;
  const int lane = tid & 63, wid = tid >> 6;
  const int wm = wid & 1, wn = wid >> 1;
  const int fq = lane >> 4, fr = lane & 15;

  f32x4 acc[4][4];
  #pragma unroll
  for (int i = 0; i < 4; ++i)
    #pragma unroll
    for (int j = 0; j < 4; ++j) acc[i][j] = (f32x4){0.f, 0.f, 0.f, 0.f};

  for (int k0 = 0; k0 < I_DIM; k0 += 32) {
    __syncthreads();
    #pragma unroll
    for (int h = 0; h < 2; ++h) {
      const int f = tid + h * 256;
      const int r = f >> 2, o = f & 3;
      const int s = (r >> 4) * 64 + o * 16 + (r & 15);
      uint4 hi, lo;
      cvt8(&x[(size_t)(m0 + r) * I_DIM + k0 + o * 8], hi, lo);
      Xhi[s] = hi; Xlo[s] = lo;
      cvt8(&Wih[(size_t)(n0 + r) * I_DIM + k0 + o * 8], hi, lo);
      Ghi[s] = hi; Glo[s] = lo;
    }
    __syncthreads();

    uint4 ahi[4], alo[4];
    #pragma unroll
    for (int mt = 0; mt < 4; ++mt) {
      ahi[mt] = Xhi[(wm * 4 + mt) * 64 + lane];
      alo[mt] = Xlo[(wm * 4 + mt) * 64 + lane];
    }
    #pragma unroll
    for (int nt = 0; nt < 4; ++nt) {
      const uint4 bhv = Ghi[(wn * 4 + nt) * 64 + lane];
      const uint4 blv = Glo[(wn * 4 + nt) * 64 + lane];
      #pragma unroll
      for (int mt = 0; mt < 4; ++mt) {
        acc[mt][nt] = __builtin_amdgcn_mfma_f32_16x16x32_bf16(
            *(const bf16x8*)&ahi[mt], *(const bf16x8*)&bhv, acc[mt][nt],
            0, 0, 0);
        acc[mt][nt] = __builtin_amdgcn_mfma_f32_16x16x32_bf16(
            *(const bf16x8*)&ahi[mt], *(const bf16x8*)&blv, acc[mt][nt],
            0, 0, 0);
        acc[mt][nt] = __builtin_amdgcn_mfma_f32_16x16x32_bf16(
            *(const bf16x8*)&alo[mt], *(const bf16x8*)&bhv, acc[mt][nt],
            0, 0, 0);
      }
    }
  }

  float bb[4];
  #pragma unroll
  for (int nt = 0; nt < 4; ++nt) {
    const int n = n0 + wn * 64 + nt * 16 + fr;
    bb[nt] = bih[n] + bhh[n];
  }
  #pragma unroll
  for (int mt = 0; mt < 4; ++mt)
    #pragma unroll
    for (int j = 0; j < 4; ++j) {
      const int m = m0 + wm * 64 + mt * 16 + fq * 4 + j;
      const bool fold = (m < B_DIM);
      #pragma unroll
      for (int nt = 0; nt < 4; ++nt) {
        const int n = n0 + wn * 64 + nt * 16 + fr;
        float v = acc[mt][nt][j] + bb[nt];
        if (fold) v = 0.01f * fmaxf(v, 0.f);
        out[(size_t)m * H_DIM + n] = v;
      }
    }
}

// =====================================================================
// Kernel B (R16): R14 scan (best: 5.06us/step) + two surgical cuts:
//  (1) out stores AFTER flag — block-private, never gate consumers;
//      wave-0 drain covers only the publish stores (vmcnt is per-WAVE,
//      so wave0's drain covers all 64 lanes' publish stores).
//  (2) drain+flag scoped to wave 0 only; merged one __syncthreads
//      (waves 1-3 stop stalling on their own out-store drains).
// Poll stays the R11/R14 single wave-parallel 32-flag check (R15 lesson).
// Parity-overwrite invariant: publish of h[t] follows the Red-sync,
// which requires all 4 waves past their polls => all 128 group flags
// >= t => every reader of parity t&1's old data has advanced.
// =====================================================================
__global__ __launch_bounds__(256) void ctrnn_scan(
    const float* __restrict__ Whh, float* out,
    unsigned long long* __restrict__ pub, unsigned* slots)
{
  __shared__ __align__(16) uint4 Whi[4096];   // 64 KB
  __shared__ __align__(16) uint4 Wlo[4096];   // 64 KB
  __shared__ __align__(16) f32x4 Red[512];    // 8 KB
  __shared__ unsigned short Hs[32][16];       // 1 KB bf16 publish staging

  const int tid = threadIdx.x, bid = blockIdx.x;
  const int nb = bid & 127, bh = bid >> 7;
  const int n0 = nb * 16, b0 = bh * 32;

  const int lane = tid & 63, wid = tid >> 6;
  const int fq = lane >> 4, fr = lane & 15;

  // ---- stage W slice ONCE: rows n0..n0+16, all k, frag-packed hi/lo ----
  for (int s = tid; s < 4096; s += 256) {
    const int kcg = s >> 6, l = s & 63;
    const int n = n0 + (l & 15), k = kcg * 32 + (l >> 4) * 8;
    uint4 hi, lo;
    cvt8(&Whh[(size_t)n * H_DIM + k], hi, lo);
    Whi[s] = hi; Wlo[s] = lo;
  }

  // ---- ownership mapping (MFMA C layout: col=lane&15=n, row=b) ----
  const int bt = tid >> 7, jh = (tid >> 6) & 1, ln = tid & 63;
  const int rfr = ln & 15, rfq = ln >> 4;
  const int bl0 = bt * 16 + rfq * 4 + jh * 2;            // local b of 1st
  const size_t oa0 = (size_t)(b0 + bl0) * H_DIM + n0 + rfr;
  const size_t oa1 = oa0 + H_DIM;

  // fp32 h state in registers (h[0] = out[0], t=0 folded in xin_gemm)
  float h0 = out[oa0];
  float h1 = out[oa1];

  // ---- publish h[0] as bf16 frags to pub parity 0, then flag = 1 ----
  Hs[bl0][rfr]     = (unsigned short)bf16_rne(h0);
  Hs[bl0 + 1][rfr] = (unsigned short)bf16_rne(h1);
  __syncthreads();   // also covers W staging completion
  if (tid < 64) {
    const int b_l = tid & 31, h8 = tid >> 5;
    const uint4 frag = *(const uint4*)&Hs[b_l][h8 * 8];
    const size_t slot = (size_t)(nb * 2 + h8) * 64 + b0 + b_l;
    astoreU(&pub[slot * 2 + 0], ((const unsigned long long*)&frag)[0]);
    astoreU(&pub[slot * 2 + 1], ((const unsigned long long*)&frag)[1]);
    asm volatile("s_waitcnt vmcnt(0)" ::: "memory");   // wave-level drain
    if (tid == 0)
      __hip_atomic_store(slots + (size_t)bid * 16, 1u, __ATOMIC_RELAXED,
                         __HIP_MEMORY_SCOPE_AGENT);
  }

  // my wave's 32 producer flags: blocks (bh, wid*32 + 0..31)
  const unsigned* myflag =
      slots + (size_t)(bh * 128 + wid * 32 + (lane & 31)) * 16;

  const int baseA64 = (wid * 4096 + fq * 64 + b0 + fr) * 2;  // u64 units
  const int baseB = wid * 1024;                              // +kc*64+lane

  for (int t = 1; t < T_DIM; ++t) {
    // prefetch xin (normal load; touch-once line, latency hides in poll)
    const float xin0 = out[(size_t)t * BH + oa0];
    const float xin1 = out[(size_t)t * BH + oa1];
    asm volatile("" :: "v"(xin0), "v"(xin1));  // keep loads here

    // ---- per-wave flag poll: my 32 producers have published h[t-1] ----
    for (int it = 0; it < (1 << 17); ++it) {
      if (__all(aloadU32(myflag) >= (unsigned)t)) break;
      __builtin_amdgcn_s_sleep(1);
    }

    const unsigned long long* pr = pub + (size_t)((t - 1) & 1) * PUB_U64;

    // ---- GEMM: agent-load A-frags straight from MALL (no fence) ----
    f32x4 acc0 = {0.f, 0.f, 0.f, 0.f}, acc1 = {0.f, 0.f, 0.f, 0.f};
    #pragma unroll
    for (int kc = 0; kc < 16; ++kc) {
      union { unsigned long long u[2]; bf16x8 v; } a0c, a1c;
      a0c.u[0] = aload64(pr + baseA64 + kc * 512 + 0);
      a0c.u[1] = aload64(pr + baseA64 + kc * 512 + 1);
      a1c.u[0] = aload64(pr + baseA64 + kc * 512 + 32);
      a1c.u[1] = aload64(pr + baseA64 + kc * 512 + 33);
      const uint4 bh4 = Whi[baseB + kc * 64 + lane];
      const uint4 bl4 = Wlo[baseB + kc * 64 + lane];
      acc0 = __builtin_amdgcn_mfma_f32_16x16x32_bf16(
          a0c.v, *(const bf16x8*)&bh4, acc0, 0, 0, 0);
      acc0 = __builtin_amdgcn_mfma_f32_16x16x32_bf16(
          a0c.v, *(const bf16x8*)&bl4, acc0, 0, 0, 0);
      acc1 = __builtin_amdgcn_mfma_f32_16x16x32_bf16(
          a1c.v, *(const bf16x8*)&bh4, acc1, 0, 0, 0);
      acc1 = __builtin_amdgcn_mfma_f32_16x16x32_bf16(
          a1c.v, *(const bf16x8*)&bl4, acc1, 0, 0, 0);
    }

    // ---- cross-wave K reduce ----
    Red[(wid * 2 + 0) * 64 + lane] = acc0;
    Red[(wid * 2 + 1) * 64 + lane] = acc1;
    __syncthreads();

    float s0 = 0.f, s1 = 0.f;
    #pragma unroll
    for (int w = 0; w < 4; ++w) {
      const float2 p = *(const float2*)(
          (const char*)&Red[(w * 2 + bt) * 64 + ln] + jh * 8);
      s0 += p.x; s1 += p.y;
    }

    // ---- leaky-relu update (fp32 register state) ----
    h0 = 0.99f * h0 + 0.01f * fmaxf(xin0 + s0, 0.f);
    h1 = 0.99f * h1 + 0.01f * fmaxf(xin1 + s1, 0.f);

    // ---- publish path FIRST (critical): Hs -> sync -> wave0
    //      publish+drain+flag.  (Red reads done at this point: the Hs
    //      writes follow the reduce loop; one sync orders them before
    //      wave0's publish reads.) ----
    Hs[bl0][rfr]     = (unsigned short)bf16_rne(h0);
    Hs[bl0 + 1][rfr] = (unsigned short)bf16_rne(h1);
    __syncthreads();
    if (t < T_DIM - 1 && tid < 64) {
      const int b_l = tid & 31, h8 = tid >> 5;
      const uint4 frag = *(const uint4*)&Hs[b_l][h8 * 8];
      const size_t slot = (size_t)(nb * 2 + h8) * 64 + b0 + b_l;
      unsigned long long* pw =
          pub + (size_t)(t & 1) * PUB_U64 + slot * 2;
      astoreU(pw + 0, ((const unsigned long long*)&frag)[0]);
      astoreU(pw + 1, ((const unsigned long long*)&frag)[1]);
      asm volatile("s_waitcnt vmcnt(0)" ::: "memory");  // wave-level drain
      if (tid == 0)
        __hip_atomic_store(slots + (size_t)bid * 16, (unsigned)(t + 1),
                           __ATOMIC_RELAXED, __HIP_MEMORY_SCOPE_AGENT);
    }

    // ---- out stores AFTER flag (block-private; off the critical path) ----
    astore4(&out[(size_t)t * BH + oa0], h0);
    astore4(&out[(size_t)t * BH + oa1], h1);
    if (t == T_DIM - 1) {
      astore4(&out[(size_t)T_DIM * BH + oa0], h0);  // h_last
      astore4(&out[(size_t)T_DIM * BH + oa1], h1);
    }
  }
}

// =====================================================================
extern "C" void kernel_launch(void* const* d_in, const int* in_sizes, int n_in,
                              void* d_out, int out_size, void* d_ws, size_t ws_size,
                              hipStream_t stream) {
  const float* x    = (const float*)d_in[0];
  const float* Wih  = (const float*)d_in[1];
  const float* bih  = (const float*)d_in[2];
  const float* Whh  = (const float*)d_in[3];
  const float* bhh  = (const float*)d_in[4];
  float* out = (float*)d_out;

  unsigned* slots = (unsigned*)d_ws;                          // 16 KB flags
  unsigned long long* pub =
      (unsigned long long*)((char*)d_ws + 32768);             // 512 KB

  hipMemsetAsync(d_ws, 0, 32768, stream);  // reset flags every call

  xin_gemm<<<dim3(2048), dim3(256), 0, stream>>>(x, Wih, bih, bhh, out);
  ctrnn_scan<<<dim3(NBLK), dim3(256), 0, stream>>>(Whh, out, pub, slots);
}

// Round 17
// 1393.216 us; speedup vs baseline: 1.8707x; 1.0609x over previous
//
#include <hip/hip_runtime.h>

// Problem dims (fixed by setup_inputs): T=256, B=64, I=512, H=2048
#define T_DIM 256
#define B_DIM 64
#define I_DIM 512
#define H_DIM 2048
#define BH (B_DIM * H_DIM)      // 131072 floats per timestep slice
#define NBLK 256                // persistent grid: 1 block per CU
#define PUB_U64 32768           // one parity: 16384 slots * 2 u64 (256 KB)

typedef __attribute__((ext_vector_type(8))) short bf16x8;
typedef __attribute__((ext_vector_type(4))) float f32x4;

// ---------------------------------------------------------------------
// Agent-scope ops (validated R4-R16): relaxed sc-bit global ops serviced
// at the device coherence point (MALL) — coherent, uncached, no fences.
// Lessons locked in: pub-style rewritten addresses MUST use agent ops
// (R12); polling must be ONE wave-parallel coalesced check (R15); the
// R14 schedule is a measured local optimum (R15/R16 edits regressed).
// ---------------------------------------------------------------------
__device__ __forceinline__ unsigned aloadU32(const unsigned* p) {
  return __hip_atomic_load(p, __ATOMIC_RELAXED, __HIP_MEMORY_SCOPE_AGENT);
}
__device__ __forceinline__ unsigned long long aload64(
    const unsigned long long* p) {
  return __hip_atomic_load(p, __ATOMIC_RELAXED, __HIP_MEMORY_SCOPE_AGENT);
}
__device__ __forceinline__ void astore4(float* p, float a) {
  union { unsigned u; float f; } c; c.f = a;
  __hip_atomic_store((unsigned*)p, c.u, __ATOMIC_RELAXED,
                     __HIP_MEMORY_SCOPE_AGENT);
}
__device__ __forceinline__ void astoreU(unsigned long long* p,
                                        unsigned long long v) {
  __hip_atomic_store(p, v, __ATOMIC_RELAXED, __HIP_MEMORY_SCOPE_AGENT);
}

// bf16 split helpers
__device__ __forceinline__ unsigned bf16_rne(float x) {
  union { float f; unsigned u; } c; c.f = x;
  return (c.u + 0x7FFFu + ((c.u >> 16) & 1u)) >> 16;
}
__device__ __forceinline__ float bf16_to_f(unsigned b) {
  union { float f; unsigned u; } c; c.u = b << 16; return c.f;
}
__device__ __forceinline__ void cvt_pair(float x0, float x1,
                                         unsigned& hi, unsigned& lo) {
  unsigned h0 = bf16_rne(x0), h1 = bf16_rne(x1);
  float r0 = x0 - bf16_to_f(h0), r1 = x1 - bf16_to_f(h1);
  unsigned l0 = bf16_rne(r0), l1 = bf16_rne(r1);
  hi = h0 | (h1 << 16);
  lo = l0 | (l1 << 16);
}
__device__ __forceinline__ void cvt8(const float* s, uint4& hi, uint4& lo) {
  float4 a = *(const float4*)s;
  float4 b = *(const float4*)(s + 4);
  cvt_pair(a.x, a.y, hi.x, lo.x);
  cvt_pair(a.z, a.w, hi.y, lo.y);
  cvt_pair(b.x, b.y, hi.z, lo.z);
  cvt_pair(b.z, b.w, hi.w, lo.w);
}

// =====================================================================
// Kernel A: MFMA split-bf16 xin GEMM (~108us).
// xin = x @ W_ih^T + b_ih + b_hh ; rows m<64 fold t=0:
// out[0] = 0.01*relu(xin[0]).
// =====================================================================
__global__ __launch_bounds__(256) void xin_gemm(
    const float* __restrict__ x, const float* __restrict__ Wih,
    const float* __restrict__ bih, const float* __restrict__ bhh,
    float* __restrict__ out)
{
  __shared__ __align__(16) uint4 Xhi[512], Xlo[512];
  __shared__ __align__(16) uint4 Ghi[512], Glo[512];

  const int tid = threadIdx.x;
  const int nb = blockIdx.x & 15, mb = blockIdx.x >> 4;
  const int m0 = mb * 128, n0 = nb * 128;
  const int lane = tid & 63, wid = tid >> 6;
  const int wm = wid & 1, wn = wid >> 1;
  const int fq = lane >> 4, fr = lane & 15;

  f32x4 acc[4][4];
  #pragma unroll
  for (int i = 0; i < 4; ++i)
    #pragma unroll
    for (int j = 0; j < 4; ++j) acc[i][j] = (f32x4){0.f, 0.f, 0.f, 0.f};

  for (int k0 = 0; k0 < I_DIM; k0 += 32) {
    __syncthreads();
    #pragma unroll
    for (int h = 0; h < 2; ++h) {
      const int f = tid + h * 256;
      const int r = f >> 2, o = f & 3;
      const int s = (r >> 4) * 64 + o * 16 + (r & 15);
      uint4 hi, lo;
      cvt8(&x[(size_t)(m0 + r) * I_DIM + k0 + o * 8], hi, lo);
      Xhi[s] = hi; Xlo[s] = lo;
      cvt8(&Wih[(size_t)(n0 + r) * I_DIM + k0 + o * 8], hi, lo);
      Ghi[s] = hi; Glo[s] = lo;
    }
    __syncthreads();

    uint4 ahi[4], alo[4];
    #pragma unroll
    for (int mt = 0; mt < 4; ++mt) {
      ahi[mt] = Xhi[(wm * 4 + mt) * 64 + lane];
      alo[mt] = Xlo[(wm * 4 + mt) * 64 + lane];
    }
    #pragma unroll
    for (int nt = 0; nt < 4; ++nt) {
      const uint4 bhv = Ghi[(wn * 4 + nt) * 64 + lane];
      const uint4 blv = Glo[(wn * 4 + nt) * 64 + lane];
      #pragma unroll
      for (int mt = 0; mt < 4; ++mt) {
        acc[mt][nt] = __builtin_amdgcn_mfma_f32_16x16x32_bf16(
            *(const bf16x8*)&ahi[mt], *(const bf16x8*)&bhv, acc[mt][nt],
            0, 0, 0);
        acc[mt][nt] = __builtin_amdgcn_mfma_f32_16x16x32_bf16(
            *(const bf16x8*)&ahi[mt], *(const bf16x8*)&blv, acc[mt][nt],
            0, 0, 0);
        acc[mt][nt] = __builtin_amdgcn_mfma_f32_16x16x32_bf16(
            *(const bf16x8*)&alo[mt], *(const bf16x8*)&bhv, acc[mt][nt],
            0, 0, 0);
      }
    }
  }

  float bb[4];
  #pragma unroll
  for (int nt = 0; nt < 4; ++nt) {
    const int n = n0 + wn * 64 + nt * 16 + fr;
    bb[nt] = bih[n] + bhh[n];
  }
  #pragma unroll
  for (int mt = 0; mt < 4; ++mt)
    #pragma unroll
    for (int j = 0; j < 4; ++j) {
      const int m = m0 + wm * 64 + mt * 16 + fq * 4 + j;
      const bool fold = (m < B_DIM);
      #pragma unroll
      for (int nt = 0; nt < 4; ++nt) {
        const int n = n0 + wn * 64 + nt * 16 + fr;
        float v = acc[mt][nt][j] + bb[nt];
        if (fold) v = 0.01f * fmaxf(v, 0.f);
        out[(size_t)m * H_DIM + n] = v;
      }
    }
}

// =====================================================================
// Kernel B: BARRIER-FREE producer-consumer scan (R11/R14 structure —
// best measured: 5.06 us/step, 1.29 ms; R12/R13/R15/R16 edits all
// regressed).
// Block (bh,nb) consumes h rows [bh*32,+32) produced only by the 128
// blocks sharing bh; wave wid needs just 32 producers nb' in [wid*32,+32).
//   producer: publish h[t] frags -> vmcnt drain -> flag = t+1 (agent).
//   consumer wave: poll its 32 producer flags >= t, then GEMM.
// Double-buffer safety: entry at step t requires all group flags >= t.
// Pub A-frags read with relaxed AGENT loads (always coherent, no fence).
// =====================================================================
__global__ __launch_bounds__(256) void ctrnn_scan(
    const float* __restrict__ Whh, float* out,
    unsigned long long* __restrict__ pub, unsigned* slots)
{
  __shared__ __align__(16) uint4 Whi[4096];   // 64 KB
  __shared__ __align__(16) uint4 Wlo[4096];   // 64 KB
  __shared__ __align__(16) f32x4 Red[512];    // 8 KB
  __shared__ unsigned short Hs[32][16];       // 1 KB bf16 publish staging

  const int tid = threadIdx.x, bid = blockIdx.x;
  const int nb = bid & 127, bh = bid >> 7;
  const int n0 = nb * 16, b0 = bh * 32;

  const int lane = tid & 63, wid = tid >> 6;
  const int fq = lane >> 4, fr = lane & 15;

  // ---- stage W slice ONCE: rows n0..n0+16, all k, frag-packed hi/lo ----
  for (int s = tid; s < 4096; s += 256) {
    const int kcg = s >> 6, l = s & 63;
    const int n = n0 + (l & 15), k = kcg * 32 + (l >> 4) * 8;
    uint4 hi, lo;
    cvt8(&Whh[(size_t)n * H_DIM + k], hi, lo);
    Whi[s] = hi; Wlo[s] = lo;
  }

  // ---- ownership mapping (MFMA C layout: col=lane&15=n, row=b) ----
  const int bt = tid >> 7, jh = (tid >> 6) & 1, ln = tid & 63;
  const int rfr = ln & 15, rfq = ln >> 4;
  const int bl0 = bt * 16 + rfq * 4 + jh * 2;            // local b of 1st
  const size_t oa0 = (size_t)(b0 + bl0) * H_DIM + n0 + rfr;
  const size_t oa1 = oa0 + H_DIM;

  // fp32 h state in registers (h[0] = out[0], t=0 folded in xin_gemm)
  float h0 = out[oa0];
  float h1 = out[oa1];

  // ---- publish h[0] as bf16 frags to pub parity 0, then flag = 1 ----
  Hs[bl0][rfr]     = (unsigned short)bf16_rne(h0);
  Hs[bl0 + 1][rfr] = (unsigned short)bf16_rne(h1);
  __syncthreads();   // also covers W staging completion
  if (tid < 64) {
    const int b_l = tid & 31, h8 = tid >> 5;
    const uint4 frag = *(const uint4*)&Hs[b_l][h8 * 8];
    const size_t slot = (size_t)(nb * 2 + h8) * 64 + b0 + b_l;
    astoreU(&pub[slot * 2 + 0], ((const unsigned long long*)&frag)[0]);
    astoreU(&pub[slot * 2 + 1], ((const unsigned long long*)&frag)[1]);
  }
  asm volatile("s_waitcnt vmcnt(0)" ::: "memory");
  if (tid == 0)
    __hip_atomic_store(slots + (size_t)bid * 16, 1u, __ATOMIC_RELAXED,
                       __HIP_MEMORY_SCOPE_AGENT);

  // my wave's 32 producer flags: blocks (bh, wid*32 + 0..31)
  const unsigned* myflag =
      slots + (size_t)(bh * 128 + wid * 32 + (lane & 31)) * 16;

  const int baseA64 = (wid * 4096 + fq * 64 + b0 + fr) * 2;  // u64 units
  const int baseB = wid * 1024;                              // +kc*64+lane

  for (int t = 1; t < T_DIM; ++t) {
    // prefetch xin (normal load; touch-once line, latency hides in poll)
    const float xin0 = out[(size_t)t * BH + oa0];
    const float xin1 = out[(size_t)t * BH + oa1];
    asm volatile("" :: "v"(xin0), "v"(xin1));  // keep loads here

    // ---- per-wave flag poll: my 32 producers have published h[t-1] ----
    for (int it = 0; it < (1 << 17); ++it) {
      if (__all(aloadU32(myflag) >= (unsigned)t)) break;
      __builtin_amdgcn_s_sleep(1);
    }

    const unsigned long long* pr = pub + (size_t)((t - 1) & 1) * PUB_U64;

    // ---- GEMM: agent-load A-frags straight from MALL (no fence) ----
    f32x4 acc0 = {0.f, 0.f, 0.f, 0.f}, acc1 = {0.f, 0.f, 0.f, 0.f};
    #pragma unroll
    for (int kc = 0; kc < 16; ++kc) {
      union { unsigned long long u[2]; bf16x8 v; } a0c, a1c;
      a0c.u[0] = aload64(pr + baseA64 + kc * 512 + 0);
      a0c.u[1] = aload64(pr + baseA64 + kc * 512 + 1);
      a1c.u[0] = aload64(pr + baseA64 + kc * 512 + 32);
      a1c.u[1] = aload64(pr + baseA64 + kc * 512 + 33);
      const uint4 bh4 = Whi[baseB + kc * 64 + lane];
      const uint4 bl4 = Wlo[baseB + kc * 64 + lane];
      acc0 = __builtin_amdgcn_mfma_f32_16x16x32_bf16(
          a0c.v, *(const bf16x8*)&bh4, acc0, 0, 0, 0);
      acc0 = __builtin_amdgcn_mfma_f32_16x16x32_bf16(
          a0c.v, *(const bf16x8*)&bl4, acc0, 0, 0, 0);
      acc1 = __builtin_amdgcn_mfma_f32_16x16x32_bf16(
          a1c.v, *(const bf16x8*)&bh4, acc1, 0, 0, 0);
      acc1 = __builtin_amdgcn_mfma_f32_16x16x32_bf16(
          a1c.v, *(const bf16x8*)&bl4, acc1, 0, 0, 0);
    }

    // ---- cross-wave K reduce ----
    Red[(wid * 2 + 0) * 64 + lane] = acc0;
    Red[(wid * 2 + 1) * 64 + lane] = acc1;
    __syncthreads();

    float s0 = 0.f, s1 = 0.f;
    #pragma unroll
    for (int w = 0; w < 4; ++w) {
      const float2 p = *(const float2*)(
          (const char*)&Red[(w * 2 + bt) * 64 + ln] + jh * 8);
      s0 += p.x; s1 += p.y;
    }

    // ---- leaky-relu update (fp32 register state) ----
    h0 = 0.99f * h0 + 0.01f * fmaxf(xin0 + s0, 0.f);
    h1 = 0.99f * h1 + 0.01f * fmaxf(xin1 + s1, 0.f);

    // ---- output stores (not on the critical path) ----
    astore4(&out[(size_t)t * BH + oa0], h0);
    astore4(&out[(size_t)t * BH + oa1], h1);
    if (t == T_DIM - 1) {
      astore4(&out[(size_t)T_DIM * BH + oa0], h0);  // h_last
      astore4(&out[(size_t)T_DIM * BH + oa1], h1);
    }

    // ---- publish bf16 h[t] -> parity t&1, drain, flag = t+1 ----
    if (t < T_DIM - 1) {
      __syncthreads();   // Red reads done; safe to reuse Hs
      Hs[bl0][rfr]     = (unsigned short)bf16_rne(h0);
      Hs[bl0 + 1][rfr] = (unsigned short)bf16_rne(h1);
      __syncthreads();
      if (tid < 64) {
        const int b_l = tid & 31, h8 = tid >> 5;
        const uint4 frag = *(const uint4*)&Hs[b_l][h8 * 8];
        const size_t slot = (size_t)(nb * 2 + h8) * 64 + b0 + b_l;
        unsigned long long* pw =
            pub + (size_t)(t & 1) * PUB_U64 + slot * 2;
        astoreU(pw + 0, ((const unsigned long long*)&frag)[0]);
        astoreU(pw + 1, ((const unsigned long long*)&frag)[1]);
      }
      asm volatile("s_waitcnt vmcnt(0)" ::: "memory");
      if (tid == 0)
        __hip_atomic_store(slots + (size_t)bid * 16, (unsigned)(t + 1),
                           __ATOMIC_RELAXED, __HIP_MEMORY_SCOPE_AGENT);
    }
  }
}

// =====================================================================
extern "C" void kernel_launch(void* const* d_in, const int* in_sizes, int n_in,
                              void* d_out, int out_size, void* d_ws, size_t ws_size,
                              hipStream_t stream) {
  const float* x    = (const float*)d_in[0];
  const float* Wih  = (const float*)d_in[1];
  const float* bih  = (const float*)d_in[2];
  const float* Whh  = (const float*)d_in[3];
  const float* bhh  = (const float*)d_in[4];
  float* out = (float*)d_out;

  unsigned* slots = (unsigned*)d_ws;                          // 16 KB flags
  unsigned long long* pub =
      (unsigned long long*)((char*)d_ws + 32768);             // 512 KB

  hipMemsetAsync(d_ws, 0, 32768, stream);  // reset flags every call

  xin_gemm<<<dim3(2048), dim3(256), 0, stream>>>(x, Wih, bih, bhh, out);
  ctrnn_scan<<<dim3(NBLK), dim3(256), 0, stream>>>(Whh, out, pub, slots);
}